// Round 12
// baseline (78.249 us; speedup 1.0000x reference)
//
#include <hip/hip_runtime.h>
#include <hip/hip_fp16.h>
#include <stdint.h>

#define NN 8192          // nodes
#define HID 256          // hidden
#define NH 4             // heads
#define HD 64            // head dim
#define NE 262144        // edges
#define WPR (NN / 32)    // bitmap words per row = 256
#define CAP 128          // max neighbors per row (Binomial(262k,1/8192): max ~57)
#define NQKV 768         // fused QKV output width
#define G1B 384          // gemm1 blocks (128x128 tiles) inside fused kernel
#define CTXP 264         // ctx LDS row stride (halves): +8 pad -> bank rotate 4

typedef __attribute__((ext_vector_type(8))) short s16x8;      // 8 halves (4 VGPRs)
typedef __attribute__((ext_vector_type(4))) float f32x4;      // MFMA C/D frag
typedef _Float16 f16x2 __attribute__((ext_vector_type(2)));   // v_dot2 operand

__device__ __forceinline__ float fdot2(f16x2 a, f16x2 b, float c) {
#if __has_builtin(__builtin_amdgcn_fdot2)
    return __builtin_amdgcn_fdot2(a, b, c, false);
#else
    return c + (float)a.x * (float)b.x + (float)a.y * (float)b.y;
#endif
}

__device__ __forceinline__ void gload_lds16(const unsigned short* g, unsigned short* l) {
    __builtin_amdgcn_global_load_lds(
        (const __attribute__((address_space(1))) unsigned int*)g,
        (__attribute__((address_space(3))) unsigned int*)l, 16, 0, 0);
}

// ---------------------------------------------------------------------------
// Zero the bitmap: 2048 blocks x 256 thr x 16B = 8 MB
// ---------------------------------------------------------------------------
__global__ __launch_bounds__(256) void zero_kernel(uint4* __restrict__ p)
{
    p[blockIdx.x * 256 + threadIdx.x] = make_uint4(0, 0, 0, 0);
}

// ---------------------------------------------------------------------------
// Fused prep: [0,1024) edge scatter | [1024,3072) X->fp16 (4/thr)
//             [3072,4096) W^T->fp16 + qkv bias
// ---------------------------------------------------------------------------
__global__ __launch_bounds__(256) void prep_kernel(
    const float* __restrict__ X,
    const float* __restrict__ Wq, const float* __restrict__ Wk,
    const float* __restrict__ Wv, const float* __restrict__ Wo,
    const float* __restrict__ bq, const float* __restrict__ bk,
    const float* __restrict__ bv, const int* __restrict__ ei,
    uint32_t* __restrict__ bitmap, unsigned short* __restrict__ Xh,
    unsigned short* __restrict__ W2Tq, unsigned short* __restrict__ W2To,
    float* __restrict__ biasq)
{
    const int b = blockIdx.x, tid = threadIdx.x;
    if (b < 1024) {                                   // ---- edge scatter ----
        int e = b * 256 + tid;
        int r = ei[e];
        int c = ei[NE + e];
        atomicOr(&bitmap[(size_t)r * WPR + (c >> 5)], 1u << (c & 31));
    } else if (b < 3072) {                            // ---- X -> fp16 ----
        int i4 = ((b - 1024) * 256 + tid) * 4;        // covers NN*HID exactly
        float4 x = *(const float4*)(X + i4);
        __half2 h0 = __floats2half2_rn(x.x, x.y);
        __half2 h1 = __floats2half2_rn(x.z, x.w);
        uint2 w;
        w.x = *(unsigned*)&h0;
        w.y = *(unsigned*)&h1;
        *(uint2*)(Xh + i4) = w;
    } else {                                          // ---- W^T -> fp16 ----
        int lin = (b - 3072) * 256 + tid;             // 262144 = 1024*256
        int n = lin >> 8, k = lin & 255;
        const float* W; int ns; unsigned short* dst;
        if (n < NQKV) {
            W  = (n < 256) ? Wq : (n < 512) ? Wk : Wv;
            ns = n & 255;
            dst = W2Tq + (size_t)n * HID + k;
            if (k == 0) {
                const float* bsrc = (n < 256) ? bq : (n < 512) ? bk : bv;
                biasq[n] = bsrc[ns];
            }
        } else {
            W = Wo; ns = n - NQKV;
            dst = W2To + (size_t)ns * HID + k;
        }
        __half h = __float2half(W[(size_t)k * HID + ns]);
        *dst = *(unsigned short*)&h;
    }
}

// ---------------------------------------------------------------------------
// fp16 MFMA GEMM tile body (BM=128, BN=128): C = A*B^T + bias, fp32 acc.
// 4 waves 2x2, each 64x64 (4x4 frags of 16x16x32 f16). K=256.
// ---------------------------------------------------------------------------
__device__ __forceinline__ void gemm_body128(
    const unsigned short* __restrict__ A, const unsigned short* __restrict__ BT,
    const float* __restrict__ bias, __half* __restrict__ Cv, int N,
    int m0, int n0, unsigned short* Alds, unsigned short* Blds)
{
    const int tid  = threadIdx.x;
    const int lane = tid & 63, wave = tid >> 6;
    const int wm = wave >> 1, wn = wave & 1;

    const int r0 = tid >> 2, cc0 = tid & 3;
    const int r1 = (tid + 256) >> 2, cc1 = (tid + 256) & 3;

    f32x4 acc[4][4];
    #pragma unroll
    for (int i = 0; i < 4; ++i)
        #pragma unroll
        for (int j = 0; j < 4; ++j)
            acc[i][j] = (f32x4){0.f, 0.f, 0.f, 0.f};

    for (int step = 0; step < 8; ++step) {
        const int kk = step * 32;
        __syncthreads();
        gload_lds16(A + (size_t)(m0 + r0) * HID + kk + cc0 * 8, &Alds[tid * 8]);
        gload_lds16(A + (size_t)(m0 + r1) * HID + kk + cc1 * 8, &Alds[(tid + 256) * 8]);
        gload_lds16(BT + (size_t)(n0 + r0) * HID + kk + cc0 * 8, &Blds[tid * 8]);
        gload_lds16(BT + (size_t)(n0 + r1) * HID + kk + cc1 * 8, &Blds[(tid + 256) * 8]);
        __syncthreads();

        s16x8 af[4], bfr[4];
        #pragma unroll
        for (int i = 0; i < 4; ++i)
            af[i] = *(const s16x8*)&Alds[(wm * 64 + i * 16 + (lane & 15)) * 32 + (lane >> 4) * 8];
        #pragma unroll
        for (int j = 0; j < 4; ++j)
            bfr[j] = *(const s16x8*)&Blds[(wn * 64 + j * 16 + (lane & 15)) * 32 + (lane >> 4) * 8];
        #pragma unroll
        for (int i = 0; i < 4; ++i)
            #pragma unroll
            for (int j = 0; j < 4; ++j)
                acc[i][j] = __builtin_amdgcn_mfma_f32_16x16x32_f16(af[i], bfr[j], acc[i][j], 0, 0, 0);
    }

    // epilogue: C/D layout col=lane&15, row=(lane>>4)*4+reg
    #pragma unroll
    for (int i = 0; i < 4; ++i) {
        #pragma unroll
        for (int j = 0; j < 4; ++j) {
            int gcol = n0 + wn * 64 + j * 16 + (lane & 15);
            float bb = bias[gcol];
            #pragma unroll
            for (int r = 0; r < 4; ++r) {
                int grow = m0 + wm * 64 + i * 16 + (lane >> 4) * 4 + r;
                Cv[(size_t)grow * N + gcol] = __float2half(acc[i][j][r] + bb);
            }
        }
    }
}

// ---------------------------------------------------------------------------
// Fused dispatch: [0, G1B) QKV GEMM (128x128 tiles, XCD swizzle) |
//                 [G1B, G1B+2048) bitmap -> capped neighbor lists (wave/row)
// ---------------------------------------------------------------------------
__global__ __launch_bounds__(256) void gemm_csr_kernel(
    const unsigned short* __restrict__ Xh, const unsigned short* __restrict__ W2Tq,
    const float* __restrict__ biasq, __half* __restrict__ QKV,
    const uint32_t* __restrict__ bitmap, int* __restrict__ nbr, int* __restrict__ cnt)
{
    __shared__ __align__(16) unsigned short Alds[128 * 32];
    __shared__ __align__(16) unsigned short Blds[128 * 32];

    if (blockIdx.x < G1B) {
        constexpr int q8 = G1B >> 3;
        const int orig = blockIdx.x;
        const int id = (orig & 7) * q8 + (orig >> 3);       // XCD-contiguous
        gemm_body128(Xh, W2Tq, biasq, QKV, NQKV,
                     (id & 63) * 128, (id >> 6) * 128, Alds, Blds);
        return;
    }
    // ---- build_csr: one wave per row ----
    const int row = (blockIdx.x - G1B) * 4 + (threadIdx.x >> 6);
    const int lane = threadIdx.x & 63;
    const uint32_t* rp = bitmap + (size_t)row * WPR + lane * 4;
    uint32_t w0 = rp[0], w1 = rp[1], w2 = rp[2], w3 = rp[3];
    int pc = __popc(w0) + __popc(w1) + __popc(w2) + __popc(w3);
    int scan = pc;
    #pragma unroll
    for (int off = 1; off < 64; off <<= 1) {
        int t = __shfl_up(scan, off);
        if (lane >= off) scan += t;
    }
    int idx = scan - pc;
    int* dst = nbr + (size_t)row * CAP;
    const int base = lane * 128;
    uint32_t ws4[4] = {w0, w1, w2, w3};
    #pragma unroll
    for (int i = 0; i < 4; ++i) {
        uint32_t w = ws4[i];
        int cb = base + i * 32;
        while (w) {
            int b = __ffs(w) - 1;
            if (idx < CAP) dst[idx] = cb + b;
            ++idx;
            w &= w - 1;
        }
    }
    if (lane == 63) cnt[row] = min(scan, CAP);
}

// ---------------------------------------------------------------------------
// Fused sparse attention + out-projection. Block = 1024 thr = 16 waves =
// 16 rows (512 blocks, 2 blocks/CU, 8192 waves = full TLP; VGPR<=64 via
// launch_bounds). Attn per wave exactly as R9/R11 (zero-LDS, batch-8,
// online softmax). Then ctx[16][CTXP] staged in LDS; wave w computes
// out-proj n-tile w via 8x 16x16x32 f16 MFMA (A from LDS, B = W2To from
// L2-hot global), + bo bias, fp32 write to d_out.
// ---------------------------------------------------------------------------
__global__ __launch_bounds__(1024, 8) void attn_out_kernel(
    const __half* __restrict__ QKV, const int* __restrict__ nbr,
    const int* __restrict__ cntg, const unsigned short* __restrict__ W2To,
    const float* __restrict__ bo, float* __restrict__ out)
{
    const int wv   = threadIdx.x >> 6;             // 0..15
    const int lane = threadIdx.x & 63;
    const int rb   = blockIdx.x * 16;              // block's first row
    const int row  = rb + wv;
    const int cnt  = cntg[row];

    __shared__ __align__(16) unsigned short ctxlds[16][CTXP];

    // ---- attention (R9 structure, per-wave) ----
    uint2 qraw = ((const uint2*)(QKV + (size_t)row * NQKV))[lane];
    union { uint2 u2; f16x2 h[2]; } uq; uq.u2 = qraw;
    const f16x2 q2a = uq.h[0], q2b = uq.h[1];

    float m = -INFINITY, l = 0.f;
    float a0 = 0.f, a1 = 0.f, a2 = 0.f, a3 = 0.f;

    for (int j0 = 0; j0 < cnt; j0 += 64) {
        int mynb = (j0 + lane < cnt) ? nbr[(size_t)row * CAP + j0 + lane] : 0;
        const int nb = min(64, cnt - j0);
        for (int b = 0; b < nb; b += 8) {
            int idx[8];
            #pragma unroll
            for (int u = 0; u < 8; ++u) idx[u] = __shfl(mynb, b + u);
            uint2 kv[8], vv[8];
            #pragma unroll
            for (int u = 0; u < 8; ++u) {          // 16 loads in flight
                const __half* base = QKV + (size_t)idx[u] * NQKV;
                kv[u] = ((const uint2*)(base + 256))[lane];
                vv[u] = ((const uint2*)(base + 512))[lane];
            }
            float s[8];
            #pragma unroll
            for (int u = 0; u < 8; ++u) {
                union { uint2 u2; f16x2 h[2]; } uk; uk.u2 = kv[u];
                float p = fdot2(q2a, uk.h[0], 0.f);
                p = fdot2(q2b, uk.h[1], p);
                #pragma unroll
                for (int off = 1; off < 16; off <<= 1) p += __shfl_xor(p, off);
                s[u] = (b + u < nb) ? p * 0.125f : -INFINITY;
            }
            float bm = s[0];
            #pragma unroll
            for (int u = 1; u < 8; ++u) bm = fmaxf(bm, s[u]);
            float mn = fmaxf(m, bm);
            float sc = expf(m - mn);               // first batch: exp(-inf)=0
            a0 *= sc; a1 *= sc; a2 *= sc; a3 *= sc; l *= sc;
            #pragma unroll
            for (int u = 0; u < 8; ++u) {
                float w = expf(s[u] - mn);         // masked: exp(-inf)=0
                l += w;
                union { uint2 u2; __half2 h[2]; } uv; uv.u2 = vv[u];
                float2 f0 = __half22float2(uv.h[0]);
                float2 f1 = __half22float2(uv.h[1]);
                a0 = fmaf(w, f0.x, a0); a1 = fmaf(w, f0.y, a1);
                a2 = fmaf(w, f1.x, a2); a3 = fmaf(w, f1.y, a3);
            }
            m = mn;
        }
    }

    {   // normalized ctx row -> LDS fp16 (cnt==0: zeros, no NaN: loop skipped)
        float rl = (cnt > 0) ? (1.f / l) : 0.f;
        __half2 o0 = __floats2half2_rn(a0 * rl, a1 * rl);
        __half2 o1 = __floats2half2_rn(a2 * rl, a3 * rl);
        uint2 w;
        w.x = *(unsigned*)&o0;
        w.y = *(unsigned*)&o1;
        *(uint2*)&ctxlds[wv][lane * 4] = w;
    }
    __syncthreads();

    // ---- out-projection: wave wv owns cols [16*wv, 16*wv+16) ----
    // A-frag: ctx[l&15][k...] from LDS; B-frag: W2To[n][k] from global (L2).
    f32x4 acc = (f32x4){0.f, 0.f, 0.f, 0.f};
    const unsigned short* bt = W2To + (size_t)(wv * 16 + (lane & 15)) * HID + (lane >> 4) * 8;
    const unsigned short* al = &ctxlds[lane & 15][(lane >> 4) * 8];
    #pragma unroll
    for (int step = 0; step < 8; ++step) {
        s16x8 af = *(const s16x8*)(al + step * 32);
        s16x8 bf = *(const s16x8*)(bt + step * 32);
        acc = __builtin_amdgcn_mfma_f32_16x16x32_f16(af, bf, acc, 0, 0, 0);
    }
    const int gcol = wv * 16 + (lane & 15);
    const float bb = bo[gcol];
    #pragma unroll
    for (int r = 0; r < 4; ++r) {
        int grow = rb + (lane >> 4) * 4 + r;
        out[(size_t)grow * HID + gcol] = acc[r] + bb;
    }
}

// ---------------------------------------------------------------------------
extern "C" void kernel_launch(void* const* d_in, const int* in_sizes, int n_in,
                              void* d_out, int out_size, void* d_ws, size_t ws_size,
                              hipStream_t stream)
{
    const float* X  = (const float*)d_in[0];
    const float* Wq = (const float*)d_in[1];
    const float* bq = (const float*)d_in[2];
    const float* Wk = (const float*)d_in[3];
    const float* bk = (const float*)d_in[4];
    const float* Wv = (const float*)d_in[5];
    const float* bv = (const float*)d_in[6];
    const float* Wo = (const float*)d_in[7];
    const float* bo = (const float*)d_in[8];
    const int*   ei = (const int*)d_in[9];
    float* out = (float*)d_out;

    char* ws = (char*)d_ws;
    uint32_t*       bitmap = (uint32_t*)ws;                       // [0, 8 MB)
    __half*         QKV    = (__half*)(ws + 8388608);             // 12,582,912 B
    unsigned short* Xh     = (unsigned short*)(ws + 20971520);    // 4 MB
    unsigned short* W2Tq   = (unsigned short*)(ws + 25165824);    // 393,216 B
    unsigned short* W2To   = (unsigned short*)(ws + 25559040);    // 131,072 B
    float*          biasq  = (float*)(ws + 25690112);             // 3,072 B
    int*            nbrL   = (int*)(ws + 25693184);               // 4 MB
    int*            cntL   = (int*)(ws + 29887488);               // 32,768 B

    zero_kernel<<<2048, 256, 0, stream>>>((uint4*)bitmap);
    prep_kernel<<<4096, 256, 0, stream>>>(
        X, Wq, Wk, Wv, Wo, bq, bk, bv, ei, bitmap, Xh, W2Tq, W2To, biasq);
    gemm_csr_kernel<<<G1B + 2048, 256, 0, stream>>>(
        Xh, W2Tq, biasq, QKV, bitmap, nbrL, cntL);
    attn_out_kernel<<<NN / 16, 1024, 0, stream>>>(
        QKV, nbrL, cntL, W2To, bo, out);
}